// Round 5
// baseline (157.930 us; speedup 1.0000x reference)
//
#include <hip/hip_runtime.h>
#include <cmath>

typedef unsigned short u16;
typedef unsigned int u32;
typedef __bf16 bf16x2 __attribute__((ext_vector_type(2)));
typedef __bf16 bf16x8 __attribute__((ext_vector_type(8)));
typedef float f32x2 __attribute__((ext_vector_type(2)));
typedef float f32x16 __attribute__((ext_vector_type(16)));

#define NQ (768*768)
#define NK (384*768)

// ---------- helpers ----------
__device__ __forceinline__ u16 f2bf(float f) {
  u32 u = __float_as_uint(f);
  u32 r = (u + 0x7FFFu + ((u >> 16) & 1u)) >> 16;  // RNE
  return (u16)r;
}
__device__ __forceinline__ u32 packbf(float a, float b) {
#if __has_builtin(__builtin_amdgcn_cvt_pk_bf16_f32)
  bf16x2 v = __builtin_amdgcn_cvt_pk_bf16_f32(a, b);
  u32 r; __builtin_memcpy(&r, &v, 4); return r;
#else
  return (u32)f2bf(a) | ((u32)f2bf(b) << 16);
#endif
}
__device__ __forceinline__ float fexp2(float x) {
#if __has_builtin(__builtin_amdgcn_exp2f)
  return __builtin_amdgcn_exp2f(x);
#else
  return exp2f(x);
#endif
}
__device__ __forceinline__ bf16x8 ldfrag(const u16* p) { bf16x8 v; __builtin_memcpy(&v, p, 16); return v; }
__device__ __forceinline__ f32x16 mfma32_(bf16x8 a, bf16x8 b, f32x16 c) {
  return __builtin_amdgcn_mfma_f32_32x32x16_bf16(a, b, c, 0, 0, 0);
}
// async global->LDS DMA, 16B per lane: LDS dest = uniform base + lane*16, src = per-lane addr.
__device__ __forceinline__ void gload_lds16(const u16* g, u16* l) {
  __builtin_amdgcn_global_load_lds((const __attribute__((address_space(1))) void*)g,
                                   (__attribute__((address_space(3))) void*)l, 16, 0, 0);
}

// Fragment-tiled layouts (ALL GEMM/attn operand loads become base + lane*16B, coalesced):
// actF / wF (K=768): [r>>5][k>>4][ lane=(r&31)+32*((k>>3)&1) ][ k&7 ]  (24576 els per 32-row group)
// K':  per (b,kvh): [s>>5][d>>4][ lane=(s&31)+32*((d>>3)&1) ][ d&7 ]
// V':  per (b,kvh): [p>>6][d>>5][ (p>>4)&3 ][ lane=(d&31)+32*((p>>3)&1) ][ p&7 ]  (p = sigma(s), bits 2<->3)
// Q':  [b][s>>5][h][d>>4][ lane=(s&31)+32*((d>>3)&1) ][ d&7 ]
__device__ __forceinline__ int fidx(int r, int k) {
  return (r >> 5) * 24576 + (k >> 4) * 512 + ((r & 31) + 32 * ((k >> 3) & 1)) * 8 + (k & 7);
}
__device__ __forceinline__ int kidx(int b6kvh, int s, int d) {
  return b6kvh * 131072 + (s >> 5) * 2048 + (d >> 4) * 512 +
         ((s & 31) + 32 * ((d >> 3) & 1)) * 8 + (d & 7);
}
__device__ __forceinline__ int qidx(int b, int s, int h, int d) {
  return ((b * 64 + (s >> 5)) * 12 + h) * 2048 + (d >> 4) * 512 +
         ((s & 31) + 32 * ((d >> 3) & 1)) * 8 + (d & 7);
}
__device__ __forceinline__ int vidx(int b6kvh, int d, int p) {
  return b6kvh * 131072 + (p >> 6) * 4096 + (d >> 5) * 2048 + ((p >> 4) & 3) * 512 +
         ((d & 31) + 32 * ((p >> 3) & 1)) * 8 + (p & 7);
}

// ---------- 1) sum(|w|) per matrix ----------
__global__ __launch_bounds__(256) void abssum_kernel(const float* __restrict__ wq, const float* __restrict__ wk,
                                                     const float* __restrict__ wv, const float* __restrict__ wo,
                                                     float* __restrict__ sums) {
  int which = blockIdx.y;
  const float* w = (which == 0) ? wq : (which == 1) ? wk : (which == 2) ? wv : wo;
  int n4 = ((which == 0 || which == 3) ? NQ : NK) >> 2;
  const float4* w4 = (const float4*)w;
  float s = 0.f;
  for (int i = blockIdx.x * blockDim.x + threadIdx.x; i < n4; i += gridDim.x * blockDim.x) {
    float4 v = w4[i];
    s += fabsf(v.x) + fabsf(v.y) + fabsf(v.z) + fabsf(v.w);
  }
  for (int off = 32; off; off >>= 1) s += __shfl_down(s, off);
  __shared__ float ls[4];
  if ((threadIdx.x & 63) == 0) ls[threadIdx.x >> 6] = s;
  __syncthreads();
  if (threadIdx.x == 0) atomicAdd(&sums[which], ls[0] + ls[1] + ls[2] + ls[3]);
}

// ---------- 2) prep: ternary-quantize weights into fragment-tiled layout + cast x + RoPE table ----------
__global__ __launch_bounds__(256) void prep_kernel(const float* __restrict__ wq, const float* __restrict__ wk,
                                                   const float* __restrict__ wv, const float* __restrict__ wo,
                                                   const float* __restrict__ sums, const float* __restrict__ x,
                                                   u16* __restrict__ qw, u16* __restrict__ woq,
                                                   u16* __restrict__ xb, float2* __restrict__ rt) {
  int i = blockIdx.x * blockDim.x + threadIdx.x;
  if (i < 221184) {
    int n = i / 96, k8 = i - n * 96;
    const float* src; float th; u16* dst; int nd;
    if (n < 768)       { src = wq + n * 768;          th = 0.7f * sums[0] * (1.f / NQ); dst = qw;  nd = n; }
    else if (n < 1152) { src = wk + (n - 768) * 768;  th = 0.7f * sums[1] * (1.f / NK); dst = qw;  nd = n; }
    else if (n < 1536) { src = wv + (n - 1152) * 768; th = 0.7f * sums[2] * (1.f / NK); dst = qw;  nd = n; }
    else               { src = wo + (n - 1536) * 768; th = 0.7f * sums[3] * (1.f / NQ); dst = woq; nd = n - 1536; }
    const float4* sp = (const float4*)(src + k8 * 8);
    float4 v0 = sp[0], v1 = sp[1];
    float e[8] = {v0.x, v0.y, v0.z, v0.w, v1.x, v1.y, v1.z, v1.w};
    u16 o[8];
#pragma unroll
    for (int j = 0; j < 8; j++)
      o[j] = f2bf((fabsf(e[j]) >= th) ? ((e[j] > 0.f) ? 1.f : -1.f) : 0.f);
    __builtin_memcpy(dst + fidx(nd, k8 * 8), o, 16);
  } else if (i < 614400) {
    int j = i - 221184;
    int m = j / 96, k8 = j - m * 96;
    const float4* xp = (const float4*)(x + m * 768 + k8 * 8);
    float4 v0 = xp[0], v1 = xp[1];
    u16 o[8] = { f2bf(v0.x), f2bf(v0.y), f2bf(v0.z), f2bf(v0.w),
                 f2bf(v1.x), f2bf(v1.y), f2bf(v1.z), f2bf(v1.w) };
    __builtin_memcpy(xb + fidx(m, k8 * 8), o, 16);
  } else {
    int j = i - 614400;                         // [0, 65536)
    int s = j >> 5, c = j & 31;
    float f = exp2f((float)c * -0.41524101186092029f);   // 10000^(-c/32)
    float sn, cs; sincosf((float)s * f, &sn, &cs);
    rt[j] = make_float2(cs, sn);
  }
}

// ---------- 3) fused QKV GEMM: m97-style LDS-staged 128x128 tile + scale + RoPE ----------
// grid (12 tn, 32 tm), 256 thr = 4 waves, wave = 64m x 64n (wm = w&1, wn = w>>1 = head in tile).
__global__ __launch_bounds__(256, 2) void gemm_qkv_kernel(const u16* __restrict__ xb, const u16* __restrict__ qw,
                                                          const float* __restrict__ sums,
                                                          const float2* __restrict__ rt,
                                                          u16* __restrict__ qb, u16* __restrict__ kb,
                                                          u16* __restrict__ vT) {
  __shared__ u16 sA[2][4][4][512];   // [buf][row-grp][kc][512]  16 KB per buf
  __shared__ u16 sB[2][4][4][512];   // [buf][col-grp][kc][512]
  int tn = blockIdx.x, tm = blockIdx.y;
  int t = threadIdx.x, lane = t & 63, w = t >> 6, c = lane & 31, g2 = lane >> 5;
  int wm = w & 1, wn = w >> 1;

  const u16* asrc = xb + (tm * 4 + w) * 24576 + lane * 8;
  const u16* bsrc = qw + (tn * 4 + w) * 24576 + lane * 8;

  auto stage = [&](int s, int bufi) {
    u16* adst = &sA[bufi][w][0][0];
    u16* bdst = &sB[bufi][w][0][0];
    const u16* ap = asrc + s * 2048;
    const u16* bp = bsrc + s * 2048;
#pragma unroll
    for (int kc = 0; kc < 4; kc++) {
      gload_lds16(ap + kc * 512, adst + kc * 512);
      gload_lds16(bp + kc * 512, bdst + kc * 512);
    }
  };

  f32x16 acc[2][2];
  acc[0][0] = (f32x16)0.f; acc[0][1] = (f32x16)0.f;
  acc[1][0] = (f32x16)0.f; acc[1][1] = (f32x16)0.f;

  stage(0, 0);
  __syncthreads();                      // vmcnt(0) drain before barrier
  for (int s = 0; s < 12; ++s) {
    int b = s & 1;
    if (s < 11) stage(s + 1, b ^ 1);    // DMA next slab while computing this one
#pragma unroll
    for (int kc = 0; kc < 4; kc++) {
      bf16x8 a0 = ldfrag(&sA[b][2 * wm][kc][lane * 8]);
      bf16x8 a1 = ldfrag(&sA[b][2 * wm + 1][kc][lane * 8]);
      bf16x8 b0 = ldfrag(&sB[b][2 * wn][kc][lane * 8]);
      bf16x8 b1 = ldfrag(&sB[b][2 * wn + 1][kc][lane * 8]);
      acc[0][0] = mfma32_(a0, b0, acc[0][0]);
      acc[0][1] = mfma32_(a0, b1, acc[0][1]);
      acc[1][0] = mfma32_(a1, b0, acc[1][0]);
      acc[1][1] = mfma32_(a1, b1, acc[1][1]);
    }
    __syncthreads();                    // readers done with buf b; stage(s+1) landed
  }

  float sq = sums[0] * (1.f / NQ) * 0.180336880111120f;  // * 0.125 * log2(e)
  float sk = sums[1] * (1.f / NK);
  float sv = sums[2] * (1.f / NK);
  if (tn < 9) {
    float sc = (tn < 6) ? sq : sk;
    int head = (tn < 6) ? (tn * 2 + wn) : ((tn - 6) * 2 + wn);
    const float2* rp = rt + c;                   // rt[s*32 + c], coalesced over lanes
#pragma unroll
    for (int mi = 0; mi < 2; mi++) {
      int mb = tm * 128 + wm * 64 + mi * 32 + 4 * g2;
#pragma unroll
      for (int r = 0; r < 16; r++) {
        int m = mb + (r & 3) + 8 * (r >> 2);
        int bb = m >> 11, s = m & 2047;
        float2 cs2 = rp[s << 5];
        float x1 = acc[mi][0][r] * sc, x2 = acc[mi][1][r] * sc;
        u16 y1 = f2bf(x1 * cs2.x - x2 * cs2.y);    // dim d = c
        u16 y2 = f2bf(x2 * cs2.x + x1 * cs2.y);    // dim d = c + 32
        if (tn < 6) {
          qb[qidx(bb, s, head, c)]      = y1;
          qb[qidx(bb, s, head, c + 32)] = y2;
        } else {
          kb[kidx(bb * 6 + head, s, c)]      = y1;
          kb[kidx(bb * 6 + head, s, c + 32)] = y2;
        }
      }
    }
  } else {
    int kvh = (tn - 9) * 2 + wn;
#pragma unroll
    for (int mi = 0; mi < 2; mi++) {
      int mb = tm * 128 + wm * 64 + mi * 32 + 4 * g2;
#pragma unroll
      for (int nb = 0; nb < 2; nb++)
#pragma unroll
        for (int r = 0; r < 16; r++) {
          int m = mb + (r & 3) + 8 * (r >> 2);
          int bb = m >> 11, s = m & 2047;
          int sp = (s & ~12) | ((s & 4) << 1) | ((s & 8) >> 1);   // sigma: swap bits 2,3
          vT[vidx(bb * 6 + kvh, nb * 32 + c, sp)] = f2bf(acc[mi][nb][r] * sv);
        }
    }
  }
}

// ---------- 4) attention: 1 q-tile per wave, high occupancy (4 waves/SIMD) ----------
// grid (12 bk, 64): y = h2*32 + qp. Block 256 = 4 waves: qi = w&1 (q-tile), kh = w>>1
// (key half, 1024 keys = 32 iters). Per-wave VGPR state ~115 fits the (256,4) cap of 128,
// giving 4 waves/SIMD so the exp (trans), pack/sum (VALU) and MFMA pipes of co-resident
// waves overlap (attn floor is the ~20us trans-pipe exp cost). Waves with the same kh read
// the same K/V slab back-to-back -> L1 hits. No loop barriers.
__device__ __forceinline__ void attn_step(const bf16x8 (&kf)[4], const bf16x8 (&vf)[2][2],
                                          const bf16x8 (&qf)[4], f32x16 (&O)[2], float& lsum) {
  f32x16 S = (f32x16)0.f;
  __builtin_amdgcn_s_setprio(1);
#pragma unroll
  for (int ks = 0; ks < 4; ks++) S = mfma32_(kf[ks], qf[ks], S);
  __builtin_amdgcn_s_setprio(0);
#pragma unroll
  for (int r = 0; r < 16; r++) S[r] = fexp2(S[r]);
  f32x2 a0 = {S[0], S[1]},  a1 = {S[2], S[3]},  a2 = {S[4], S[5]},  a3 = {S[6], S[7]};
  f32x2 a4 = {S[8], S[9]},  a5 = {S[10], S[11]}, a6 = {S[12], S[13]}, a7 = {S[14], S[15]};
  f32x2 b0 = a0 + a1, b1 = a2 + a3, b2 = a4 + a5, b3 = a6 + a7;
  f32x2 c0 = b0 + b1, c1 = b2 + b3;
  f32x2 d = c0 + c1;
  lsum += d.x + d.y;
  u32 P[8];
#pragma unroll
  for (int j = 0; j < 8; j++) P[j] = packbf(S[2 * j], S[2 * j + 1]);
  bf16x8 PA0, PA1;
  __builtin_memcpy(&PA0, &P[0], 16);
  __builtin_memcpy(&PA1, &P[4], 16);
  __builtin_amdgcn_s_setprio(1);
  O[0] = mfma32_(PA0, vf[0][0], O[0]);
  O[1] = mfma32_(PA0, vf[1][0], O[1]);
  O[0] = mfma32_(PA1, vf[0][1], O[0]);
  O[1] = mfma32_(PA1, vf[1][1], O[1]);
  __builtin_amdgcn_s_setprio(0);
}

__global__ __launch_bounds__(256, 4) void attn_kernel(const u16* __restrict__ qb, const u16* __restrict__ kb,
                                                      const u16* __restrict__ vT, u16* __restrict__ ab) {
  __shared__ float Obuf[4][32][66];
  __shared__ float Lbuf[4][32];
  int bk = blockIdx.x;
  int b = bk / 6, kvh = bk % 6;
  int qp = blockIdx.y & 31, h2 = blockIdx.y >> 5;
  int h = kvh * 2 + h2;
  int t = threadIdx.x, lane = t & 63, w = t >> 6, c = lane & 31, g2 = lane >> 5;
  int qi = w & 1, kh = w >> 1;
  int qt = qp * 2 + qi;

  const u16* qbase = qb + ((b * 64 + qt) * 12 + h) * 2048 + lane * 8;
  bf16x8 qf[4];
#pragma unroll
  for (int ks = 0; ks < 4; ks++) qf[ks] = ldfrag(qbase + ks * 512);

  f32x16 fz = (f32x16)0.f;
  f32x16 O[2] = {fz, fz};
  float lsum = 0.f;

  const u16* Kb = kb + bk * 131072;
  const u16* Vb = vT + bk * 131072;

  for (int it = 0; it < 32; ++it) {
    int g = kh * 32 + it;                       // this wave's key group (32 keys)
    const u16* kt = Kb + g * 2048 + lane * 8;
    const u16* vt = Vb + (g >> 1) * 4096 + (g & 1) * 1024 + lane * 8;
    bf16x8 kf[4], vf[2][2];
#pragma unroll
    for (int ks = 0; ks < 4; ks++) kf[ks] = ldfrag(kt + ks * 512);
#pragma unroll
    for (int dn = 0; dn < 2; dn++)
#pragma unroll
      for (int ksv = 0; ksv < 2; ksv++)
        vf[dn][ksv] = ldfrag(vt + dn * 2048 + ksv * 512);
    attn_step(kf, vf, qf, O, lsum);
  }

  float ltot = lsum + __shfl_xor(lsum, 32);     // combine the two 16-key row-halves per query
  if (g2 == 0) Lbuf[w][c] = ltot;
#pragma unroll
  for (int dn = 0; dn < 2; dn++)
#pragma unroll
    for (int r = 0; r < 16; r++)
      Obuf[w][(r & 3) + 8 * (r >> 2) + 4 * g2][dn * 32 + c] = O[dn][r];
  __syncthreads();
  {
    int hn = t >> 7, qq = (t >> 2) & 31, dc = (t & 3) * 16;   // hn = q-tile, combine kh pair
    float l = Lbuf[hn][qq] + Lbuf[hn + 2][qq];
    float inv = 1.f / l;
    u16 o[16];
#pragma unroll
    for (int j = 0; j < 16; j++)
      o[j] = f2bf((Obuf[hn][qq][dc + j] + Obuf[hn + 2][qq][dc + j]) * inv);
    int mg = b * 64 + qp * 2 + hn;
    u16* dst = ab + mg * 24576 + ((h * 64 + dc) >> 4) * 512 + qq * 8;
    __builtin_memcpy(dst, o, 16);            // d8-group 0
    __builtin_memcpy(dst + 256, o + 8, 16);  // d8-group 1
  }
}

// ---------- 5) output projection GEMM: LDS-staged 128m x 64n tile -> fp32 ----------
// grid (12 tn, 32 tm), 4 waves: wm = w&1 (64-row half), wn = w>>1 (32-col half); each wave
// computes 64x32. Staging per K-step: A 16 KB (wave w -> row-group w), B 8 KB (wave w ->
// col-group w>>1, kc-half w&1). Double-buffered, one barrier per step. Per-output traffic
// 2.1x lower than the direct 64x64 version.
__global__ __launch_bounds__(256, 3) void gemm_out_kernel(const u16* __restrict__ ab, const u16* __restrict__ woq,
                                                          const float* __restrict__ sums, float* __restrict__ out) {
  __shared__ u16 sA[2][4][4][512];   // [buf][row-grp][kc][512]  16 KB per buf
  __shared__ u16 sB[2][2][4][512];   // [buf][col-grp][kc][512]   8 KB per buf
  int tn = blockIdx.x, tm = blockIdx.y;
  int t = threadIdx.x, lane = t & 63, w = t >> 6, c = lane & 31, g2 = lane >> 5;
  int wm = w & 1, wn = w >> 1;

  const u16* asrc = ab + (tm * 4 + w) * 24576 + lane * 8;
  const u16* bsrc = woq + (tn * 2 + (w >> 1)) * 24576 + lane * 8;
  int kc0 = (w & 1) * 2;

  auto stage = [&](int s, int bufi) {
    const u16* ap = asrc + s * 2048;
    u16* adst = &sA[bufi][w][0][0];
#pragma unroll
    for (int kc = 0; kc < 4; kc++) gload_lds16(ap + kc * 512, adst + kc * 512);
    const u16* bp = bsrc + s * 2048;
    u16* bdst = &sB[bufi][w >> 1][0][0];
#pragma unroll
    for (int j = 0; j < 2; j++) gload_lds16(bp + (kc0 + j) * 512, bdst + (kc0 + j) * 512);
  };

  f32x16 acc[2]; acc[0] = (f32x16)0.f; acc[1] = (f32x16)0.f;

  stage(0, 0);
  __syncthreads();
  for (int s = 0; s < 12; ++s) {
    int b = s & 1;
    if (s < 11) stage(s + 1, b ^ 1);
#pragma unroll
    for (int kc = 0; kc < 4; kc++) {
      bf16x8 a0 = ldfrag(&sA[b][2 * wm][kc][lane * 8]);
      bf16x8 a1 = ldfrag(&sA[b][2 * wm + 1][kc][lane * 8]);
      bf16x8 bf = ldfrag(&sB[b][wn][kc][lane * 8]);
      acc[0] = mfma32_(a0, bf, acc[0]);
      acc[1] = mfma32_(a1, bf, acc[1]);
    }
    __syncthreads();
  }

  float so = sums[3] * (1.f / NQ);
#pragma unroll
  for (int mi = 0; mi < 2; mi++) {
    int mb = tm * 128 + wm * 64 + mi * 32 + 4 * g2;
#pragma unroll
    for (int r = 0; r < 16; r++) {
      int m = mb + (r & 3) + 8 * (r >> 2);
      out[m * 768 + tn * 64 + wn * 32 + c] = acc[mi][r] * so;
    }
  }
}

// ---------- launch ----------
extern "C" void kernel_launch(void* const* d_in, const int* in_sizes, int n_in,
                              void* d_out, int out_size, void* d_ws, size_t ws_size,
                              hipStream_t stream) {
  const float* x  = (const float*)d_in[0];
  const float* wq = (const float*)d_in[1];
  const float* wk = (const float*)d_in[2];
  const float* wv = (const float*)d_in[3];
  const float* wo = (const float*)d_in[4];
  float* out = (float*)d_out;
  char* ws = (char*)d_ws;

  float* sums = (float*)ws;                    // 16 B
  u16* qw  = (u16*)(ws + 256);                 // ternary QKV weights, fragment-tiled (1536 rows)
  u16* woq = (u16*)(ws + 2359552);             // ternary O weights, fragment-tiled (768 rows)
  u16* xb  = (u16*)(ws + 3539200);             // x fragment-tiled
  u16* qb  = (u16*)(ws + 9830656);             // Q' fragment-tiled
  u16* kb  = (u16*)(ws + 16122112);            // K' fragment-tiled
  u16* vT  = (u16*)(ws + 19267840);            // V' fragment-tiled, key-permuted
  u16* ab  = (u16*)(ws + 22413568);            // attn out fragment-tiled (ends at 28705024)
  float2* rt = (float2*)(ws + 28705024);       // RoPE table [2048][32] (cos, sin) = 512 KB

  hipMemsetAsync(sums, 0, 16, stream);
  dim3 blk(256);
  abssum_kernel<<<dim3(64, 4), blk, 0, stream>>>(wq, wk, wv, wo, sums);
  prep_kernel<<<dim3(2656), blk, 0, stream>>>(wq, wk, wv, wo, sums, x, qw, woq, xb, rt);
  gemm_qkv_kernel<<<dim3(12, 32), blk, 0, stream>>>(xb, qw, sums, rt, qb, kb, vT);
  attn_kernel<<<dim3(12, 64), blk, 0, stream>>>(qb, kb, vT, ab);
  gemm_out_kernel<<<dim3(12, 32), blk, 0, stream>>>(ab, woq, sums, out);
}

// Round 6
// 156.978 us; speedup vs baseline: 1.0061x; 1.0061x over previous
//
#include <hip/hip_runtime.h>
#include <cmath>

typedef unsigned short u16;
typedef unsigned int u32;
typedef __bf16 bf16x2 __attribute__((ext_vector_type(2)));
typedef __bf16 bf16x8 __attribute__((ext_vector_type(8)));
typedef float f32x2 __attribute__((ext_vector_type(2)));
typedef float f32x16 __attribute__((ext_vector_type(16)));

#define NQ (768*768)
#define NK (384*768)

// ---------- helpers ----------
__device__ __forceinline__ u16 f2bf(float f) {
  u32 u = __float_as_uint(f);
  u32 r = (u + 0x7FFFu + ((u >> 16) & 1u)) >> 16;  // RNE
  return (u16)r;
}
__device__ __forceinline__ u32 packbf(float a, float b) {
#if __has_builtin(__builtin_amdgcn_cvt_pk_bf16_f32)
  bf16x2 v = __builtin_amdgcn_cvt_pk_bf16_f32(a, b);
  u32 r; __builtin_memcpy(&r, &v, 4); return r;
#else
  return (u32)f2bf(a) | ((u32)f2bf(b) << 16);
#endif
}
__device__ __forceinline__ float fexp2(float x) {
#if __has_builtin(__builtin_amdgcn_exp2f)
  return __builtin_amdgcn_exp2f(x);
#else
  return exp2f(x);
#endif
}
__device__ __forceinline__ bf16x8 ldfrag(const u16* p) { bf16x8 v; __builtin_memcpy(&v, p, 16); return v; }
__device__ __forceinline__ f32x16 mfma32_(bf16x8 a, bf16x8 b, f32x16 c) {
  return __builtin_amdgcn_mfma_f32_32x32x16_bf16(a, b, c, 0, 0, 0);
}
// async global->LDS DMA, 16B per lane: LDS dest = uniform base + lane*16, src = per-lane addr.
__device__ __forceinline__ void gload_lds16(const u16* g, u16* l) {
  __builtin_amdgcn_global_load_lds((const __attribute__((address_space(1))) void*)g,
                                   (__attribute__((address_space(3))) void*)l, 16, 0, 0);
}

// Fragment-tiled layouts (ALL GEMM/attn operand loads become base + lane*16B, coalesced):
// actF / wF (K=768): [r>>5][k>>4][ lane=(r&31)+32*((k>>3)&1) ][ k&7 ]  (24576 els per 32-row group)
// K':  per (b,kvh): [s>>5][d>>4][ lane=(s&31)+32*((d>>3)&1) ][ d&7 ]
// V':  per (b,kvh): [p>>6][d>>5][ (p>>4)&3 ][ lane=(d&31)+32*((p>>3)&1) ][ p&7 ]  (p = sigma(s), bits 2<->3)
// Q':  [b][s>>5][h][d>>4][ lane=(s&31)+32*((d>>3)&1) ][ d&7 ]
__device__ __forceinline__ int fidx(int r, int k) {
  return (r >> 5) * 24576 + (k >> 4) * 512 + ((r & 31) + 32 * ((k >> 3) & 1)) * 8 + (k & 7);
}
__device__ __forceinline__ int kidx(int b6kvh, int s, int d) {
  return b6kvh * 131072 + (s >> 5) * 2048 + (d >> 4) * 512 +
         ((s & 31) + 32 * ((d >> 3) & 1)) * 8 + (d & 7);
}
__device__ __forceinline__ int qidx(int b, int s, int h, int d) {
  return ((b * 64 + (s >> 5)) * 12 + h) * 2048 + (d >> 4) * 512 +
         ((s & 31) + 32 * ((d >> 3) & 1)) * 8 + (d & 7);
}
__device__ __forceinline__ int vidx(int b6kvh, int d, int p) {
  return b6kvh * 131072 + (p >> 6) * 4096 + (d >> 5) * 2048 + ((p >> 4) & 3) * 512 +
         ((d & 31) + 32 * ((p >> 3) & 1)) * 8 + (p & 7);
}

// ---------- 1) sum(|w|) per matrix ----------
__global__ __launch_bounds__(256) void abssum_kernel(const float* __restrict__ wq, const float* __restrict__ wk,
                                                     const float* __restrict__ wv, const float* __restrict__ wo,
                                                     float* __restrict__ sums) {
  int which = blockIdx.y;
  const float* w = (which == 0) ? wq : (which == 1) ? wk : (which == 2) ? wv : wo;
  int n4 = ((which == 0 || which == 3) ? NQ : NK) >> 2;
  const float4* w4 = (const float4*)w;
  float s = 0.f;
  for (int i = blockIdx.x * blockDim.x + threadIdx.x; i < n4; i += gridDim.x * blockDim.x) {
    float4 v = w4[i];
    s += fabsf(v.x) + fabsf(v.y) + fabsf(v.z) + fabsf(v.w);
  }
  for (int off = 32; off; off >>= 1) s += __shfl_down(s, off);
  __shared__ float ls[4];
  if ((threadIdx.x & 63) == 0) ls[threadIdx.x >> 6] = s;
  __syncthreads();
  if (threadIdx.x == 0) atomicAdd(&sums[which], ls[0] + ls[1] + ls[2] + ls[3]);
}

// ---------- 2) prep: ternary-quantize weights into fragment-tiled layout + cast x + RoPE table ----------
__global__ __launch_bounds__(256) void prep_kernel(const float* __restrict__ wq, const float* __restrict__ wk,
                                                   const float* __restrict__ wv, const float* __restrict__ wo,
                                                   const float* __restrict__ sums, const float* __restrict__ x,
                                                   u16* __restrict__ qw, u16* __restrict__ woq,
                                                   u16* __restrict__ xb, float2* __restrict__ rt) {
  int i = blockIdx.x * blockDim.x + threadIdx.x;
  if (i < 221184) {
    int n = i / 96, k8 = i - n * 96;
    const float* src; float th; u16* dst; int nd;
    if (n < 768)       { src = wq + n * 768;          th = 0.7f * sums[0] * (1.f / NQ); dst = qw;  nd = n; }
    else if (n < 1152) { src = wk + (n - 768) * 768;  th = 0.7f * sums[1] * (1.f / NK); dst = qw;  nd = n; }
    else if (n < 1536) { src = wv + (n - 1152) * 768; th = 0.7f * sums[2] * (1.f / NK); dst = qw;  nd = n; }
    else               { src = wo + (n - 1536) * 768; th = 0.7f * sums[3] * (1.f / NQ); dst = woq; nd = n - 1536; }
    const float4* sp = (const float4*)(src + k8 * 8);
    float4 v0 = sp[0], v1 = sp[1];
    float e[8] = {v0.x, v0.y, v0.z, v0.w, v1.x, v1.y, v1.z, v1.w};
    u16 o[8];
#pragma unroll
    for (int j = 0; j < 8; j++)
      o[j] = f2bf((fabsf(e[j]) >= th) ? ((e[j] > 0.f) ? 1.f : -1.f) : 0.f);
    __builtin_memcpy(dst + fidx(nd, k8 * 8), o, 16);
  } else if (i < 614400) {
    int j = i - 221184;
    int m = j / 96, k8 = j - m * 96;
    const float4* xp = (const float4*)(x + m * 768 + k8 * 8);
    float4 v0 = xp[0], v1 = xp[1];
    u16 o[8] = { f2bf(v0.x), f2bf(v0.y), f2bf(v0.z), f2bf(v0.w),
                 f2bf(v1.x), f2bf(v1.y), f2bf(v1.z), f2bf(v1.w) };
    __builtin_memcpy(xb + fidx(m, k8 * 8), o, 16);
  } else {
    int j = i - 614400;                         // [0, 65536)
    int s = j >> 5, c = j & 31;
    float f = exp2f((float)c * -0.41524101186092029f);   // 10000^(-c/32)
    float sn, cs; sincosf((float)s * f, &sn, &cs);
    rt[j] = make_float2(cs, sn);
  }
}

// ---------- 3) fused QKV GEMM: m97-style LDS-staged 128x128 tile + scale + RoPE ----------
// grid (12 tn, 32 tm), 256 thr = 4 waves, wave = 64m x 64n (wm = w&1, wn = w>>1 = head in tile).
__global__ __launch_bounds__(256, 2) void gemm_qkv_kernel(const u16* __restrict__ xb, const u16* __restrict__ qw,
                                                          const float* __restrict__ sums,
                                                          const float2* __restrict__ rt,
                                                          u16* __restrict__ qb, u16* __restrict__ kb,
                                                          u16* __restrict__ vT) {
  __shared__ u16 sA[2][4][4][512];   // [buf][row-grp][kc][512]  16 KB per buf
  __shared__ u16 sB[2][4][4][512];   // [buf][col-grp][kc][512]
  int tn = blockIdx.x, tm = blockIdx.y;
  int t = threadIdx.x, lane = t & 63, w = t >> 6, c = lane & 31, g2 = lane >> 5;
  int wm = w & 1, wn = w >> 1;

  const u16* asrc = xb + (tm * 4 + w) * 24576 + lane * 8;
  const u16* bsrc = qw + (tn * 4 + w) * 24576 + lane * 8;

  auto stage = [&](int s, int bufi) {
    u16* adst = &sA[bufi][w][0][0];
    u16* bdst = &sB[bufi][w][0][0];
    const u16* ap = asrc + s * 2048;
    const u16* bp = bsrc + s * 2048;
#pragma unroll
    for (int kc = 0; kc < 4; kc++) {
      gload_lds16(ap + kc * 512, adst + kc * 512);
      gload_lds16(bp + kc * 512, bdst + kc * 512);
    }
  };

  f32x16 acc[2][2];
  acc[0][0] = (f32x16)0.f; acc[0][1] = (f32x16)0.f;
  acc[1][0] = (f32x16)0.f; acc[1][1] = (f32x16)0.f;

  stage(0, 0);
  __syncthreads();                      // vmcnt(0) drain before barrier
  for (int s = 0; s < 12; ++s) {
    int b = s & 1;
    if (s < 11) stage(s + 1, b ^ 1);    // DMA next slab while computing this one
#pragma unroll
    for (int kc = 0; kc < 4; kc++) {
      bf16x8 a0 = ldfrag(&sA[b][2 * wm][kc][lane * 8]);
      bf16x8 a1 = ldfrag(&sA[b][2 * wm + 1][kc][lane * 8]);
      bf16x8 b0 = ldfrag(&sB[b][2 * wn][kc][lane * 8]);
      bf16x8 b1 = ldfrag(&sB[b][2 * wn + 1][kc][lane * 8]);
      acc[0][0] = mfma32_(a0, b0, acc[0][0]);
      acc[0][1] = mfma32_(a0, b1, acc[0][1]);
      acc[1][0] = mfma32_(a1, b0, acc[1][0]);
      acc[1][1] = mfma32_(a1, b1, acc[1][1]);
    }
    __syncthreads();                    // readers done with buf b; stage(s+1) landed
  }

  float sq = sums[0] * (1.f / NQ) * 0.180336880111120f;  // * 0.125 * log2(e)
  float sk = sums[1] * (1.f / NK);
  float sv = sums[2] * (1.f / NK);
  if (tn < 9) {
    float sc = (tn < 6) ? sq : sk;
    int head = (tn < 6) ? (tn * 2 + wn) : ((tn - 6) * 2 + wn);
    const float2* rp = rt + c;                   // rt[s*32 + c], coalesced over lanes
#pragma unroll
    for (int mi = 0; mi < 2; mi++) {
      int mb = tm * 128 + wm * 64 + mi * 32 + 4 * g2;
#pragma unroll
      for (int r = 0; r < 16; r++) {
        int m = mb + (r & 3) + 8 * (r >> 2);
        int bb = m >> 11, s = m & 2047;
        float2 cs2 = rp[s << 5];
        float x1 = acc[mi][0][r] * sc, x2 = acc[mi][1][r] * sc;
        u16 y1 = f2bf(x1 * cs2.x - x2 * cs2.y);    // dim d = c
        u16 y2 = f2bf(x2 * cs2.x + x1 * cs2.y);    // dim d = c + 32
        if (tn < 6) {
          qb[qidx(bb, s, head, c)]      = y1;
          qb[qidx(bb, s, head, c + 32)] = y2;
        } else {
          kb[kidx(bb * 6 + head, s, c)]      = y1;
          kb[kidx(bb * 6 + head, s, c + 32)] = y2;
        }
      }
    }
  } else {
    int kvh = (tn - 9) * 2 + wn;
#pragma unroll
    for (int mi = 0; mi < 2; mi++) {
      int mb = tm * 128 + wm * 64 + mi * 32 + 4 * g2;
#pragma unroll
      for (int nb = 0; nb < 2; nb++)
#pragma unroll
        for (int r = 0; r < 16; r++) {
          int m = mb + (r & 3) + 8 * (r >> 2);
          int bb = m >> 11, s = m & 2047;
          int sp = (s & ~12) | ((s & 4) << 1) | ((s & 8) >> 1);   // sigma: swap bits 2,3
          vT[vidx(bb * 6 + kvh, nb * 32 + c, sp)] = f2bf(acc[mi][nb][r] * sv);
        }
    }
  }
}

// ---------- 4) attention: barrier-free loop, 4-way key split, 2 q-tiles per wave ----------
// grid (12 bk, 64): y = h2*32 + qp. Block 256 = 4 waves; wave w owns key quarter w
// (16 iters x 32 keys) and processes BOTH q-tiles from registers. No loop barriers; the two
// q-tiles' QK->exp->PV chains overlap. lsum via packed f32x2 adds; s_setprio(1) around MFMA
// clusters. (R4 best-measured configuration; (256,4) 1-q-tile variant regressed + showed a
// pathological 30 ms profiled dispatch -> reverted.)
__device__ __forceinline__ void attn_step(const bf16x8 (&kf)[4], const bf16x8 (&vf)[2][2],
                                          const bf16x8 (&qf)[4], f32x16 (&O)[2], float& lsum) {
  f32x16 S = (f32x16)0.f;
  __builtin_amdgcn_s_setprio(1);
#pragma unroll
  for (int ks = 0; ks < 4; ks++) S = mfma32_(kf[ks], qf[ks], S);
  __builtin_amdgcn_s_setprio(0);
#pragma unroll
  for (int r = 0; r < 16; r++) S[r] = fexp2(S[r]);
  f32x2 a0 = {S[0], S[1]},  a1 = {S[2], S[3]},  a2 = {S[4], S[5]},  a3 = {S[6], S[7]};
  f32x2 a4 = {S[8], S[9]},  a5 = {S[10], S[11]}, a6 = {S[12], S[13]}, a7 = {S[14], S[15]};
  f32x2 b0 = a0 + a1, b1 = a2 + a3, b2 = a4 + a5, b3 = a6 + a7;
  f32x2 c0 = b0 + b1, c1 = b2 + b3;
  f32x2 d = c0 + c1;
  lsum += d.x + d.y;
  u32 P[8];
#pragma unroll
  for (int j = 0; j < 8; j++) P[j] = packbf(S[2 * j], S[2 * j + 1]);
  bf16x8 PA0, PA1;
  __builtin_memcpy(&PA0, &P[0], 16);
  __builtin_memcpy(&PA1, &P[4], 16);
  __builtin_amdgcn_s_setprio(1);
  O[0] = mfma32_(PA0, vf[0][0], O[0]);
  O[1] = mfma32_(PA0, vf[1][0], O[1]);
  O[0] = mfma32_(PA1, vf[0][1], O[0]);
  O[1] = mfma32_(PA1, vf[1][1], O[1]);
  __builtin_amdgcn_s_setprio(0);
}

__global__ __launch_bounds__(256, 3) void attn_kernel(const u16* __restrict__ qb, const u16* __restrict__ kb,
                                                      const u16* __restrict__ vT, u16* __restrict__ ab) {
  __shared__ float Obuf[4][32][66];
  __shared__ float Lbuf[4][32];
  int bk = blockIdx.x;
  int b = bk / 6, kvh = bk % 6;
  int qp = blockIdx.y & 31, h2 = blockIdx.y >> 5;
  int h = kvh * 2 + h2;
  int t = threadIdx.x, lane = t & 63, w = t >> 6, c = lane & 31, g2 = lane >> 5;

  const u16* q0 = qb + ((b * 64 + qp * 2) * 12 + h) * 2048 + lane * 8;
  const u16* q1 = q0 + 12 * 2048;
  bf16x8 qf0[4], qf1[4];
#pragma unroll
  for (int ks = 0; ks < 4; ks++) { qf0[ks] = ldfrag(q0 + ks * 512); qf1[ks] = ldfrag(q1 + ks * 512); }

  f32x16 fz = (f32x16)0.f;
  f32x16 O0[2] = {fz, fz}, O1[2] = {fz, fz};
  float lsum0 = 0.f, lsum1 = 0.f;

  const u16* Kb = kb + bk * 131072;
  const u16* Vb = vT + bk * 131072;

  for (int it = 0; it < 16; ++it) {
    int g = w * 16 + it;                        // this wave's key group (32 keys)
    const u16* kt = Kb + g * 2048 + lane * 8;
    const u16* vt = Vb + (g >> 1) * 4096 + (g & 1) * 1024 + lane * 8;
    bf16x8 kf[4], vf[2][2];
#pragma unroll
    for (int ks = 0; ks < 4; ks++) kf[ks] = ldfrag(kt + ks * 512);
#pragma unroll
    for (int dn = 0; dn < 2; dn++)
#pragma unroll
      for (int ksv = 0; ksv < 2; ksv++)
        vf[dn][ksv] = ldfrag(vt + dn * 2048 + ksv * 512);
    attn_step(kf, vf, qf0, O0, lsum0);
    attn_step(kf, vf, qf1, O1, lsum1);
  }

  float lt0 = lsum0 + __shfl_xor(lsum0, 32);    // combine g2 key-row halves per query col
  float lt1 = lsum1 + __shfl_xor(lsum1, 32);

  // two reduce passes (qi = 0, 1): 4 wave-partials -> one q-tile of output each
#pragma unroll
  for (int qi = 0; qi < 2; qi++) {
    if (qi) __syncthreads();                    // pass-0 reads done before overwrite
    if (g2 == 0) Lbuf[w][c] = qi ? lt1 : lt0;
    const f32x16* Ow = qi ? O1 : O0;
#pragma unroll
    for (int dn = 0; dn < 2; dn++)
#pragma unroll
      for (int r = 0; r < 16; r++)
        Obuf[w][(r & 3) + 8 * (r >> 2) + 4 * g2][dn * 32 + c] = Ow[dn][r];
    __syncthreads();
    int qq = t >> 3, col8 = (t & 7) * 8;
    float l = Lbuf[0][qq] + Lbuf[1][qq] + Lbuf[2][qq] + Lbuf[3][qq];
    float inv = 1.f / l;
    u16 o[8];
#pragma unroll
    for (int j = 0; j < 8; j++)
      o[j] = f2bf((Obuf[0][qq][col8 + j] + Obuf[1][qq][col8 + j] +
                   Obuf[2][qq][col8 + j] + Obuf[3][qq][col8 + j]) * inv);
    int mg = b * 64 + qp * 2 + qi;
    u16* dst = ab + mg * 24576 + ((h * 64 + col8) >> 4) * 512 + ((col8 >> 3) & 1) * 256 + qq * 8;
    __builtin_memcpy(dst, o, 16);
  }
}

// ---------- 5) output projection GEMM: LDS-staged 128m x 64n tile -> fp32 ----------
// grid (12 tn, 32 tm), 4 waves: wm = w&1 (64-row half), wn = w>>1 (32-col half); each wave
// computes 64x32. Staging per K-step: A 16 KB (wave w -> row-group w), B 8 KB (wave w ->
// col-group w>>1, kc-half w&1). Double-buffered, one barrier per step.
__global__ __launch_bounds__(256, 3) void gemm_out_kernel(const u16* __restrict__ ab, const u16* __restrict__ woq,
                                                          const float* __restrict__ sums, float* __restrict__ out) {
  __shared__ u16 sA[2][4][4][512];   // [buf][row-grp][kc][512]  16 KB per buf
  __shared__ u16 sB[2][2][4][512];   // [buf][col-grp][kc][512]   8 KB per buf
  int tn = blockIdx.x, tm = blockIdx.y;
  int t = threadIdx.x, lane = t & 63, w = t >> 6, c = lane & 31, g2 = lane >> 5;
  int wm = w & 1, wn = w >> 1;

  const u16* asrc = ab + (tm * 4 + w) * 24576 + lane * 8;
  const u16* bsrc = woq + (tn * 2 + (w >> 1)) * 24576 + lane * 8;
  int kc0 = (w & 1) * 2;

  auto stage = [&](int s, int bufi) {
    const u16* ap = asrc + s * 2048;
    u16* adst = &sA[bufi][w][0][0];
#pragma unroll
    for (int kc = 0; kc < 4; kc++) gload_lds16(ap + kc * 512, adst + kc * 512);
    const u16* bp = bsrc + s * 2048;
    u16* bdst = &sB[bufi][w >> 1][0][0];
#pragma unroll
    for (int j = 0; j < 2; j++) gload_lds16(bp + (kc0 + j) * 512, bdst + (kc0 + j) * 512);
  };

  f32x16 acc[2]; acc[0] = (f32x16)0.f; acc[1] = (f32x16)0.f;

  stage(0, 0);
  __syncthreads();
  for (int s = 0; s < 12; ++s) {
    int b = s & 1;
    if (s < 11) stage(s + 1, b ^ 1);
#pragma unroll
    for (int kc = 0; kc < 4; kc++) {
      bf16x8 a0 = ldfrag(&sA[b][2 * wm][kc][lane * 8]);
      bf16x8 a1 = ldfrag(&sA[b][2 * wm + 1][kc][lane * 8]);
      bf16x8 bf = ldfrag(&sB[b][wn][kc][lane * 8]);
      acc[0] = mfma32_(a0, bf, acc[0]);
      acc[1] = mfma32_(a1, bf, acc[1]);
    }
    __syncthreads();
  }

  float so = sums[3] * (1.f / NQ);
#pragma unroll
  for (int mi = 0; mi < 2; mi++) {
    int mb = tm * 128 + wm * 64 + mi * 32 + 4 * g2;
#pragma unroll
    for (int r = 0; r < 16; r++) {
      int m = mb + (r & 3) + 8 * (r >> 2);
      out[m * 768 + tn * 64 + wn * 32 + c] = acc[mi][r] * so;
    }
  }
}

// ---------- launch ----------
extern "C" void kernel_launch(void* const* d_in, const int* in_sizes, int n_in,
                              void* d_out, int out_size, void* d_ws, size_t ws_size,
                              hipStream_t stream) {
  const float* x  = (const float*)d_in[0];
  const float* wq = (const float*)d_in[1];
  const float* wk = (const float*)d_in[2];
  const float* wv = (const float*)d_in[3];
  const float* wo = (const float*)d_in[4];
  float* out = (float*)d_out;
  char* ws = (char*)d_ws;

  float* sums = (float*)ws;                    // 16 B
  u16* qw  = (u16*)(ws + 256);                 // ternary QKV weights, fragment-tiled (1536 rows)
  u16* woq = (u16*)(ws + 2359552);             // ternary O weights, fragment-tiled (768 rows)
  u16* xb  = (u16*)(ws + 3539200);             // x fragment-tiled
  u16* qb  = (u16*)(ws + 9830656);             // Q' fragment-tiled
  u16* kb  = (u16*)(ws + 16122112);            // K' fragment-tiled
  u16* vT  = (u16*)(ws + 19267840);            // V' fragment-tiled, key-permuted
  u16* ab  = (u16*)(ws + 22413568);            // attn out fragment-tiled (ends at 28705024)
  float2* rt = (float2*)(ws + 28705024);       // RoPE table [2048][32] (cos, sin) = 512 KB

  hipMemsetAsync(sums, 0, 16, stream);
  dim3 blk(256);
  abssum_kernel<<<dim3(64, 4), blk, 0, stream>>>(wq, wk, wv, wo, sums);
  prep_kernel<<<dim3(2656), blk, 0, stream>>>(wq, wk, wv, wo, sums, x, qw, woq, xb, rt);
  gemm_qkv_kernel<<<dim3(12, 32), blk, 0, stream>>>(xb, qw, sums, rt, qb, kb, vT);
  attn_kernel<<<dim3(12, 64), blk, 0, stream>>>(qb, kb, vT, ab);
  gemm_out_kernel<<<dim3(12, 32), blk, 0, stream>>>(ab, woq, sums, out);
}

// Round 8
// 149.563 us; speedup vs baseline: 1.0559x; 1.0496x over previous
//
#include <hip/hip_runtime.h>
#include <cmath>

typedef unsigned short u16;
typedef unsigned int u32;
typedef __bf16 bf16x2 __attribute__((ext_vector_type(2)));
typedef __bf16 bf16x8 __attribute__((ext_vector_type(8)));
typedef float f32x2 __attribute__((ext_vector_type(2)));
typedef float f32x16 __attribute__((ext_vector_type(16)));

#define NQ (768*768)
#define NK (384*768)

// ---------- helpers ----------
__device__ __forceinline__ u16 f2bf(float f) {
  u32 u = __float_as_uint(f);
  u32 r = (u + 0x7FFFu + ((u >> 16) & 1u)) >> 16;  // RNE
  return (u16)r;
}
__device__ __forceinline__ u32 packbf(float a, float b) {
#if __has_builtin(__builtin_amdgcn_cvt_pk_bf16_f32)
  bf16x2 v = __builtin_amdgcn_cvt_pk_bf16_f32(a, b);
  u32 r; __builtin_memcpy(&r, &v, 4); return r;
#else
  return (u32)f2bf(a) | ((u32)f2bf(b) << 16);
#endif
}
__device__ __forceinline__ float fexp2(float x) {
#if __has_builtin(__builtin_amdgcn_exp2f)
  return __builtin_amdgcn_exp2f(x);
#else
  return exp2f(x);
#endif
}
__device__ __forceinline__ bf16x8 ldfrag(const u16* p) { bf16x8 v; __builtin_memcpy(&v, p, 16); return v; }
__device__ __forceinline__ f32x16 mfma32_(bf16x8 a, bf16x8 b, f32x16 c) {
  return __builtin_amdgcn_mfma_f32_32x32x16_bf16(a, b, c, 0, 0, 0);
}
// async global->LDS DMA, 16B per lane: LDS dest = uniform base + lane*16, src = per-lane addr.
__device__ __forceinline__ void gload_lds16(const u16* g, u16* l) {
  __builtin_amdgcn_global_load_lds((const __attribute__((address_space(1))) void*)g,
                                   (__attribute__((address_space(3))) void*)l, 16, 0, 0);
}
// bijective XCD swizzle for 768-block 1-D grids (768 = 8 XCDs x 96): XCD i owns a
// CONTIGUOUS virtual range [i*96, (i+1)*96) so its L2 working set is 1/8 of the grid's.
__device__ __forceinline__ int xcd_swz768(int lin) { return (lin & 7) * 96 + (lin >> 3); }

// Fragment-tiled layouts (ALL GEMM/attn operand loads become base + lane*16B, coalesced):
// actF / wF (K=768): [r>>5][k>>4][ lane=(r&31)+32*((k>>3)&1) ][ k&7 ]  (24576 els per 32-row group)
// K':  per (b,kvh): [s>>5][d>>4][ lane=(s&31)+32*((d>>3)&1) ][ d&7 ]
// V':  per (b,kvh): [p>>6][d>>5][ (p>>4)&3 ][ lane=(d&31)+32*((p>>3)&1) ][ p&7 ]  (p = sigma(s), bits 2<->3)
// Q':  [b][s>>5][h][d>>4][ lane=(s&31)+32*((d>>3)&1) ][ d&7 ]
__device__ __forceinline__ int fidx(int r, int k) {
  return (r >> 5) * 24576 + (k >> 4) * 512 + ((r & 31) + 32 * ((k >> 3) & 1)) * 8 + (k & 7);
}
__device__ __forceinline__ int kidx(int b6kvh, int s, int d) {
  return b6kvh * 131072 + (s >> 5) * 2048 + (d >> 4) * 512 +
         ((s & 31) + 32 * ((d >> 3) & 1)) * 8 + (d & 7);
}
__device__ __forceinline__ int qidx(int b, int s, int h, int d) {
  return ((b * 64 + (s >> 5)) * 12 + h) * 2048 + (d >> 4) * 512 +
         ((s & 31) + 32 * ((d >> 3) & 1)) * 8 + (d & 7);
}
__device__ __forceinline__ int vidx(int b6kvh, int d, int p) {
  return b6kvh * 131072 + (p >> 6) * 4096 + (d >> 5) * 2048 + ((p >> 4) & 3) * 512 +
         ((d & 31) + 32 * ((p >> 3) & 1)) * 8 + (p & 7);
}

// ---------- 1) sum(|w|) per matrix ----------
__global__ __launch_bounds__(256) void abssum_kernel(const float* __restrict__ wq, const float* __restrict__ wk,
                                                     const float* __restrict__ wv, const float* __restrict__ wo,
                                                     float* __restrict__ sums) {
  int which = blockIdx.y;
  const float* w = (which == 0) ? wq : (which == 1) ? wk : (which == 2) ? wv : wo;
  int n4 = ((which == 0 || which == 3) ? NQ : NK) >> 2;
  const float4* w4 = (const float4*)w;
  float s = 0.f;
  for (int i = blockIdx.x * blockDim.x + threadIdx.x; i < n4; i += gridDim.x * blockDim.x) {
    float4 v = w4[i];
    s += fabsf(v.x) + fabsf(v.y) + fabsf(v.z) + fabsf(v.w);
  }
  for (int off = 32; off; off >>= 1) s += __shfl_down(s, off);
  __shared__ float ls[4];
  if ((threadIdx.x & 63) == 0) ls[threadIdx.x >> 6] = s;
  __syncthreads();
  if (threadIdx.x == 0) atomicAdd(&sums[which], ls[0] + ls[1] + ls[2] + ls[3]);
}

// ---------- 2) prep: ternary-quantize weights into fragment-tiled layout + cast x + RoPE table ----------
__global__ __launch_bounds__(256) void prep_kernel(const float* __restrict__ wq, const float* __restrict__ wk,
                                                   const float* __restrict__ wv, const float* __restrict__ wo,
                                                   const float* __restrict__ sums, const float* __restrict__ x,
                                                   u16* __restrict__ qw, u16* __restrict__ woq,
                                                   u16* __restrict__ xb, float2* __restrict__ rt) {
  int i = blockIdx.x * blockDim.x + threadIdx.x;
  if (i < 221184) {
    int n = i / 96, k8 = i - n * 96;
    const float* src; float th; u16* dst; int nd;
    if (n < 768)       { src = wq + n * 768;          th = 0.7f * sums[0] * (1.f / NQ); dst = qw;  nd = n; }
    else if (n < 1152) { src = wk + (n - 768) * 768;  th = 0.7f * sums[1] * (1.f / NK); dst = qw;  nd = n; }
    else if (n < 1536) { src = wv + (n - 1152) * 768; th = 0.7f * sums[2] * (1.f / NK); dst = qw;  nd = n; }
    else               { src = wo + (n - 1536) * 768; th = 0.7f * sums[3] * (1.f / NQ); dst = woq; nd = n - 1536; }
    const float4* sp = (const float4*)(src + k8 * 8);
    float4 v0 = sp[0], v1 = sp[1];
    float e[8] = {v0.x, v0.y, v0.z, v0.w, v1.x, v1.y, v1.z, v1.w};
    u16 o[8];
#pragma unroll
    for (int j = 0; j < 8; j++)
      o[j] = f2bf((fabsf(e[j]) >= th) ? ((e[j] > 0.f) ? 1.f : -1.f) : 0.f);
    __builtin_memcpy(dst + fidx(nd, k8 * 8), o, 16);
  } else if (i < 614400) {
    int j = i - 221184;
    int m = j / 96, k8 = j - m * 96;
    const float4* xp = (const float4*)(x + m * 768 + k8 * 8);
    float4 v0 = xp[0], v1 = xp[1];
    u16 o[8] = { f2bf(v0.x), f2bf(v0.y), f2bf(v0.z), f2bf(v0.w),
                 f2bf(v1.x), f2bf(v1.y), f2bf(v1.z), f2bf(v1.w) };
    __builtin_memcpy(xb + fidx(m, k8 * 8), o, 16);
  } else {
    int j = i - 614400;                         // [0, 65536)
    int s = j >> 5, c = j & 31;
    float f = exp2f((float)c * -0.41524101186092029f);   // 10000^(-c/32)
    float sn, cs; sincosf((float)s * f, &sn, &cs);
    rt[j] = make_float2(cs, sn);
  }
}

// ---------- 3) fused QKV GEMM: m97 single-buffer 2-barrier, 64m x 128n tile + RoPE ----------
// 1-D grid 768 (XCD-swizzled: tm = v/12 contiguous per XCD -> A panel 786 KB + B 2.4 MB
// fit the 4 MB XCD L2). 4 waves: wm = w&1 (32-row half), wn = w>>1 (64-col half = head).
// Per K-step (BK=64): 24 KB slab (A 8 KB + B 16 KB) staged once by the 4 waves (6 x 1 KB
// gload_lds16 each), 2 barriers, no double buffer -- at 3 resident blocks/CU the implicit
// wave overlap covers the stage stall (m97/m99: explicit dbuf adds nothing at this depth),
// and the 768-block grid removes the (256,2) 128x128 version's 2:1 CU load imbalance.
__global__ __launch_bounds__(256, 3) void gemm_qkv_kernel(const u16* __restrict__ xb, const u16* __restrict__ qw,
                                                          const float* __restrict__ sums,
                                                          const float2* __restrict__ rt,
                                                          u16* __restrict__ qb, u16* __restrict__ kb,
                                                          u16* __restrict__ vT) {
  __shared__ u16 sm[24 * 512];   // chunks 0-7 = A (2 grp x 4 kc), 8-23 = B (4 grp x 4 kc)
  int v = xcd_swz768(blockIdx.x);
  int tm = v / 12, tn = v - tm * 12;
  int t = threadIdx.x, lane = t & 63, w = t >> 6, c = lane & 31, g2 = lane >> 5;
  int wm = w & 1, wn = w >> 1;
  int wn8 = wn * 8;

  f32x16 acc[2]; acc[0] = (f32x16)0.f; acc[1] = (f32x16)0.f;

  for (int s = 0; s < 12; ++s) {
#pragma unroll
    for (int i = 0; i < 6; i++) {
      int ch = w * 6 + i;
      const u16* src = (ch < 8)
        ? xb + (tm * 2 + (ch >> 2)) * 24576 + (s * 4 + (ch & 3)) * 512 + lane * 8
        : qw + (tn * 4 + (ch >> 2) - 2) * 24576 + (s * 4 + (ch & 3)) * 512 + lane * 8;
      gload_lds16(src, sm + ch * 512);
    }
    __syncthreads();                  // vmcnt(0) drained -> slab s visible
#pragma unroll
    for (int kc = 0; kc < 4; kc++) {
      bf16x8 a  = ldfrag(sm + (wm * 4 + kc) * 512 + lane * 8);
      bf16x8 b0 = ldfrag(sm + (8 + wn8 + kc) * 512 + lane * 8);
      bf16x8 b1 = ldfrag(sm + (12 + wn8 + kc) * 512 + lane * 8);
      acc[0] = mfma32_(a, b0, acc[0]);
      acc[1] = mfma32_(a, b1, acc[1]);
    }
    __syncthreads();                  // readers done before next stage overwrites
  }

  float sq = sums[0] * (1.f / NQ) * 0.180336880111120f;  // * 0.125 * log2(e)
  float sk = sums[1] * (1.f / NK);
  float sv = sums[2] * (1.f / NK);
  int mb = tm * 64 + wm * 32 + 4 * g2;
  if (tn < 9) {
    float sc = (tn < 6) ? sq : sk;
    int head = (tn < 6) ? (tn * 2 + wn) : ((tn - 6) * 2 + wn);
    const float2* rp = rt + c;                   // rt[s*32 + c], coalesced over lanes
#pragma unroll
    for (int r = 0; r < 16; r++) {
      int m = mb + (r & 3) + 8 * (r >> 2);
      int bb = m >> 11, s = m & 2047;
      float2 cs2 = rp[s << 5];
      float x1 = acc[0][r] * sc, x2 = acc[1][r] * sc;
      u16 y1 = f2bf(x1 * cs2.x - x2 * cs2.y);    // dim d = c
      u16 y2 = f2bf(x2 * cs2.x + x1 * cs2.y);    // dim d = c + 32
      if (tn < 6) {
        qb[qidx(bb, s, head, c)]      = y1;
        qb[qidx(bb, s, head, c + 32)] = y2;
      } else {
        kb[kidx(bb * 6 + head, s, c)]      = y1;
        kb[kidx(bb * 6 + head, s, c + 32)] = y2;
      }
    }
  } else {
    int kvh = (tn - 9) * 2 + wn;
#pragma unroll
    for (int nb = 0; nb < 2; nb++)
#pragma unroll
      for (int r = 0; r < 16; r++) {
        int m = mb + (r & 3) + 8 * (r >> 2);
        int bb = m >> 11, s = m & 2047;
        int sp = (s & ~12) | ((s & 4) << 1) | ((s & 8) >> 1);   // sigma: swap bits 2,3
        vT[vidx(bb * 6 + kvh, nb * 32 + c, sp)] = f2bf(acc[nb][r] * sv);
      }
  }
}

// ---------- 4) attention: barrier-free loop, 4-way key split, 2 q-tiles per wave ----------
// 1-D grid 768, XCD-swizzled so each XCD owns a contiguous 96-block range = ~1.5 (b,kvh)
// K/V sets (768 KB, L2-resident) instead of all 12 (6 MB > 4 MB L2 -> thrash). Wave w owns
// key quarter w and processes BOTH q-tiles from registers; no loop barriers; setprio around
// MFMA clusters; packed f32x2 lsum tree. (R4 best-measured attn configuration.)
__device__ __forceinline__ void attn_step(const bf16x8 (&kf)[4], const bf16x8 (&vf)[2][2],
                                          const bf16x8 (&qf)[4], f32x16 (&O)[2], float& lsum) {
  f32x16 S = (f32x16)0.f;
  __builtin_amdgcn_s_setprio(1);
#pragma unroll
  for (int ks = 0; ks < 4; ks++) S = mfma32_(kf[ks], qf[ks], S);
  __builtin_amdgcn_s_setprio(0);
#pragma unroll
  for (int r = 0; r < 16; r++) S[r] = fexp2(S[r]);
  f32x2 a0 = {S[0], S[1]},  a1 = {S[2], S[3]},  a2 = {S[4], S[5]},  a3 = {S[6], S[7]};
  f32x2 a4 = {S[8], S[9]},  a5 = {S[10], S[11]}, a6 = {S[12], S[13]}, a7 = {S[14], S[15]};
  f32x2 b0 = a0 + a1, b1 = a2 + a3, b2 = a4 + a5, b3 = a6 + a7;
  f32x2 c0 = b0 + b1, c1 = b2 + b3;
  f32x2 d = c0 + c1;
  lsum += d.x + d.y;
  u32 P[8];
#pragma unroll
  for (int j = 0; j < 8; j++) P[j] = packbf(S[2 * j], S[2 * j + 1]);
  bf16x8 PA0, PA1;
  __builtin_memcpy(&PA0, &P[0], 16);
  __builtin_memcpy(&PA1, &P[4], 16);
  __builtin_amdgcn_s_setprio(1);
  O[0] = mfma32_(PA0, vf[0][0], O[0]);
  O[1] = mfma32_(PA0, vf[1][0], O[1]);
  O[0] = mfma32_(PA1, vf[0][1], O[0]);
  O[1] = mfma32_(PA1, vf[1][1], O[1]);
  __builtin_amdgcn_s_setprio(0);
}

__global__ __launch_bounds__(256, 3) void attn_kernel(const u16* __restrict__ qb, const u16* __restrict__ kb,
                                                      const u16* __restrict__ vT, u16* __restrict__ ab) {
  __shared__ float Obuf[4][32][66];
  __shared__ float Lbuf[4][32];
  int v = xcd_swz768(blockIdx.x);
  int bk = v >> 6, y = v & 63;
  int b = bk / 6, kvh = bk % 6;
  int qp = y & 31, h2 = y >> 5;
  int h = kvh * 2 + h2;
  int t = threadIdx.x, lane = t & 63, w = t >> 6, c = lane & 31, g2 = lane >> 5;

  const u16* q0 = qb + ((b * 64 + qp * 2) * 12 + h) * 2048 + lane * 8;
  const u16* q1 = q0 + 12 * 2048;
  bf16x8 qf0[4], qf1[4];
#pragma unroll
  for (int ks = 0; ks < 4; ks++) { qf0[ks] = ldfrag(q0 + ks * 512); qf1[ks] = ldfrag(q1 + ks * 512); }

  f32x16 fz = (f32x16)0.f;
  f32x16 O0[2] = {fz, fz}, O1[2] = {fz, fz};
  float lsum0 = 0.f, lsum1 = 0.f;

  const u16* Kb = kb + bk * 131072;
  const u16* Vb = vT + bk * 131072;

  for (int it = 0; it < 16; ++it) {
    int g = w * 16 + it;                        // this wave's key group (32 keys)
    const u16* kt = Kb + g * 2048 + lane * 8;
    const u16* vt = Vb + (g >> 1) * 4096 + (g & 1) * 1024 + lane * 8;
    bf16x8 kf[4], vf[2][2];
#pragma unroll
    for (int ks = 0; ks < 4; ks++) kf[ks] = ldfrag(kt + ks * 512);
#pragma unroll
    for (int dn = 0; dn < 2; dn++)
#pragma unroll
      for (int ksv = 0; ksv < 2; ksv++)
        vf[dn][ksv] = ldfrag(vt + dn * 2048 + ksv * 512);
    attn_step(kf, vf, qf0, O0, lsum0);
    attn_step(kf, vf, qf1, O1, lsum1);
  }

  float lt0 = lsum0 + __shfl_xor(lsum0, 32);    // combine g2 key-row halves per query col
  float lt1 = lsum1 + __shfl_xor(lsum1, 32);

  // two reduce passes (qi = 0, 1): 4 wave-partials -> one q-tile of output each
#pragma unroll
  for (int qi = 0; qi < 2; qi++) {
    if (qi) __syncthreads();                    // pass-0 reads done before overwrite
    if (g2 == 0) Lbuf[w][c] = qi ? lt1 : lt0;
    const f32x16* Ow = qi ? O1 : O0;
#pragma unroll
    for (int dn = 0; dn < 2; dn++)
#pragma unroll
      for (int r = 0; r < 16; r++)
        Obuf[w][(r & 3) + 8 * (r >> 2) + 4 * g2][dn * 32 + c] = Ow[dn][r];
    __syncthreads();
    int qq = t >> 3, col8 = (t & 7) * 8;
    float l = Lbuf[0][qq] + Lbuf[1][qq] + Lbuf[2][qq] + Lbuf[3][qq];
    float inv = 1.f / l;
    u16 o[8];
#pragma unroll
    for (int j = 0; j < 8; j++)
      o[j] = f2bf((Obuf[0][qq][col8 + j] + Obuf[1][qq][col8 + j] +
                   Obuf[2][qq][col8 + j] + Obuf[3][qq][col8 + j]) * inv);
    int mg = b * 64 + qp * 2 + qi;
    u16* dst = ab + mg * 24576 + ((h * 64 + col8) >> 4) * 512 + ((col8 >> 3) & 1) * 256 + qq * 8;
    __builtin_memcpy(dst, o, 16);
  }
}

// ---------- 5) output projection GEMM (direct, barrier-free, SW-pipelined, 64m x 64n) -> fp32 ----------
// R4's proven version (R6 isolated the staged variant at +3.6 us -> reverted). 1-D grid 768,
// XCD-swizzled (tm contiguous per XCD).
__global__ __launch_bounds__(256, 3) void gemm_out_kernel(const u16* __restrict__ ab, const u16* __restrict__ woq,
                                                          const float* __restrict__ sums, float* __restrict__ out) {
  int v = xcd_swz768(blockIdx.x);
  int tm = v / 12, tn = v - tm * 12;
  int t = threadIdx.x, lane = t & 63, w = t >> 6, c = lane & 31, g2 = lane >> 5;
  int wm = w & 1, wn = w >> 1;
  const u16* abase = ab + (tm * 2 + wm) * 24576 + lane * 8;
  const u16* bbase = woq + (tn * 2 + wn) * 24576 + lane * 8;
  f32x16 acc = (f32x16)0.f;
  bf16x8 aA[4], bA[4], aB[4], bB[4];
#pragma unroll
  for (int ks = 0; ks < 4; ks++) {
    aA[ks] = ldfrag(abase + ks * 512);
    bA[ks] = ldfrag(bbase + ks * 512);
  }
#pragma unroll
  for (int kk = 0; kk < 48; kk += 8) {
#pragma unroll
    for (int ks = 0; ks < 4; ks++) {
      aB[ks] = ldfrag(abase + (kk + 4 + ks) * 512);
      bB[ks] = ldfrag(bbase + (kk + 4 + ks) * 512);
    }
#pragma unroll
    for (int ks = 0; ks < 4; ks++) acc = mfma32_(aA[ks], bA[ks], acc);
    if (kk + 8 < 48) {
#pragma unroll
      for (int ks = 0; ks < 4; ks++) {
        aA[ks] = ldfrag(abase + (kk + 8 + ks) * 512);
        bA[ks] = ldfrag(bbase + (kk + 8 + ks) * 512);
      }
    }
#pragma unroll
    for (int ks = 0; ks < 4; ks++) acc = mfma32_(aB[ks], bB[ks], acc);
  }
  float so = sums[3] * (1.f / NQ);
  int mb = tm * 64 + wm * 32 + 4 * g2;
#pragma unroll
  for (int r = 0; r < 16; r++) {
    int m = mb + (r & 3) + 8 * (r >> 2);
    out[m * 768 + tn * 64 + wn * 32 + c] = acc[r] * so;
  }
}

// ---------- launch ----------
extern "C" void kernel_launch(void* const* d_in, const int* in_sizes, int n_in,
                              void* d_out, int out_size, void* d_ws, size_t ws_size,
                              hipStream_t stream) {
  const float* x  = (const float*)d_in[0];
  const float* wq = (const float*)d_in[1];
  const float* wk = (const float*)d_in[2];
  const float* wv = (const float*)d_in[3];
  const float* wo = (const float*)d_in[4];
  float* out = (float*)d_out;
  char* ws = (char*)d_ws;

  float* sums = (float*)ws;                    // 16 B
  u16* qw  = (u16*)(ws + 256);                 // ternary QKV weights, fragment-tiled (1536 rows)
  u16* woq = (u16*)(ws + 2359552);             // ternary O weights, fragment-tiled (768 rows)
  u16* xb  = (u16*)(ws + 3539200);             // x fragment-tiled
  u16* qb  = (u16*)(ws + 9830656);             // Q' fragment-tiled
  u16* kb  = (u16*)(ws + 16122112);            // K' fragment-tiled
  u16* vT  = (u16*)(ws + 19267840);            // V' fragment-tiled, key-permuted
  u16* ab  = (u16*)(ws + 22413568);            // attn out fragment-tiled (ends at 28705024)
  float2* rt = (float2*)(ws + 28705024);       // RoPE table [2048][32] (cos, sin) = 512 KB

  hipMemsetAsync(sums, 0, 16, stream);
  dim3 blk(256);
  abssum_kernel<<<dim3(64, 4), blk, 0, stream>>>(wq, wk, wv, wo, sums);
  prep_kernel<<<dim3(2656), blk, 0, stream>>>(wq, wk, wv, wo, sums, x, qw, woq, xb, rt);
  gemm_qkv_kernel<<<dim3(768), blk, 0, stream>>>(xb, qw, sums, rt, qb, kb, vT);
  attn_kernel<<<dim3(768), blk, 0, stream>>>(qb, kb, vT, ab);
  gemm_out_kernel<<<dim3(768), blk, 0, stream>>>(ab, woq, sums, out);
}

// Round 10
// 145.875 us; speedup vs baseline: 1.0826x; 1.0253x over previous
//
#include <hip/hip_runtime.h>
#include <cmath>

typedef unsigned short u16;
typedef unsigned int u32;
typedef __bf16 bf16x2 __attribute__((ext_vector_type(2)));
typedef __bf16 bf16x8 __attribute__((ext_vector_type(8)));
typedef float f32x2 __attribute__((ext_vector_type(2)));
typedef float f32x16 __attribute__((ext_vector_type(16)));

#define NQ (768*768)
#define NK (384*768)

// ---------- helpers ----------
__device__ __forceinline__ u16 f2bf(float f) {
  u32 u = __float_as_uint(f);
  u32 r = (u + 0x7FFFu + ((u >> 16) & 1u)) >> 16;  // RNE
  return (u16)r;
}
__device__ __forceinline__ u32 packbf(float a, float b) {
#if __has_builtin(__builtin_amdgcn_cvt_pk_bf16_f32)
  bf16x2 v = __builtin_amdgcn_cvt_pk_bf16_f32(a, b);
  u32 r; __builtin_memcpy(&r, &v, 4); return r;
#else
  return (u32)f2bf(a) | ((u32)f2bf(b) << 16);
#endif
}
__device__ __forceinline__ float fexp2(float x) {
#if __has_builtin(__builtin_amdgcn_exp2f)
  return __builtin_amdgcn_exp2f(x);
#else
  return exp2f(x);
#endif
}
__device__ __forceinline__ bf16x8 ldfrag(const u16* p) { bf16x8 v; __builtin_memcpy(&v, p, 16); return v; }
__device__ __forceinline__ f32x16 mfma32_(bf16x8 a, bf16x8 b, f32x16 c) {
  return __builtin_amdgcn_mfma_f32_32x32x16_bf16(a, b, c, 0, 0, 0);
}
// async global->LDS DMA, 16B per lane: LDS dest = uniform base + lane*16, src = per-lane addr.
__device__ __forceinline__ void gload_lds16(const u16* g, u16* l) {
  __builtin_amdgcn_global_load_lds((const __attribute__((address_space(1))) void*)g,
                                   (__attribute__((address_space(3))) void*)l, 16, 0, 0);
}
// bijective XCD swizzle for 768-block 1-D grids (768 = 8 XCDs x 96): XCD i owns a
// CONTIGUOUS virtual range [i*96, (i+1)*96) so its L2 working set is 1/8 of the grid's.
__device__ __forceinline__ int xcd_swz768(int lin) { return (lin & 7) * 96 + (lin >> 3); }

// Fragment-tiled layouts (ALL GEMM/attn operand loads become base + lane*16B, coalesced):
// actF / wF (K=768): [r>>5][k>>4][ lane=(r&31)+32*((k>>3)&1) ][ k&7 ]  (24576 els per 32-row group)
// K':  per (b,kvh): [s>>5][d>>4][ lane=(s&31)+32*((d>>3)&1) ][ d&7 ]
// V':  per (b,kvh): [p>>6][d>>5][ (p>>4)&3 ][ lane=(d&31)+32*((p>>3)&1) ][ p&7 ]  (p = sigma(s), bits 2<->3)
// Q':  [b][s>>5][h][d>>4][ lane=(s&31)+32*((d>>3)&1) ][ d&7 ]
__device__ __forceinline__ int fidx(int r, int k) {
  return (r >> 5) * 24576 + (k >> 4) * 512 + ((r & 31) + 32 * ((k >> 3) & 1)) * 8 + (k & 7);
}
__device__ __forceinline__ int kidx(int b6kvh, int s, int d) {
  return b6kvh * 131072 + (s >> 5) * 2048 + (d >> 4) * 512 +
         ((s & 31) + 32 * ((d >> 3) & 1)) * 8 + (d & 7);
}
__device__ __forceinline__ int qidx(int b, int s, int h, int d) {
  return ((b * 64 + (s >> 5)) * 12 + h) * 2048 + (d >> 4) * 512 +
         ((s & 31) + 32 * ((d >> 3) & 1)) * 8 + (d & 7);
}
__device__ __forceinline__ int vidx(int b6kvh, int d, int p) {
  return b6kvh * 131072 + (p >> 6) * 4096 + (d >> 5) * 2048 + ((p >> 4) & 3) * 512 +
         ((d & 31) + 32 * ((p >> 3) & 1)) * 8 + (p & 7);
}

// ---------- 1) sum(|w|) per matrix ----------
__global__ __launch_bounds__(256) void abssum_kernel(const float* __restrict__ wq, const float* __restrict__ wk,
                                                     const float* __restrict__ wv, const float* __restrict__ wo,
                                                     float* __restrict__ sums) {
  int which = blockIdx.y;
  const float* w = (which == 0) ? wq : (which == 1) ? wk : (which == 2) ? wv : wo;
  int n4 = ((which == 0 || which == 3) ? NQ : NK) >> 2;
  const float4* w4 = (const float4*)w;
  float s = 0.f;
  for (int i = blockIdx.x * blockDim.x + threadIdx.x; i < n4; i += gridDim.x * blockDim.x) {
    float4 v = w4[i];
    s += fabsf(v.x) + fabsf(v.y) + fabsf(v.z) + fabsf(v.w);
  }
  for (int off = 32; off; off >>= 1) s += __shfl_down(s, off);
  __shared__ float ls[4];
  if ((threadIdx.x & 63) == 0) ls[threadIdx.x >> 6] = s;
  __syncthreads();
  if (threadIdx.x == 0) atomicAdd(&sums[which], ls[0] + ls[1] + ls[2] + ls[3]);
}

// ---------- 2) prep: ternary-quantize weights into fragment-tiled layout + cast x + RoPE table ----------
__global__ __launch_bounds__(256) void prep_kernel(const float* __restrict__ wq, const float* __restrict__ wk,
                                                   const float* __restrict__ wv, const float* __restrict__ wo,
                                                   const float* __restrict__ sums, const float* __restrict__ x,
                                                   u16* __restrict__ qw, u16* __restrict__ woq,
                                                   u16* __restrict__ xb, float2* __restrict__ rt) {
  int i = blockIdx.x * blockDim.x + threadIdx.x;
  if (i < 221184) {
    int n = i / 96, k8 = i - n * 96;
    const float* src; float th; u16* dst; int nd;
    if (n < 768)       { src = wq + n * 768;          th = 0.7f * sums[0] * (1.f / NQ); dst = qw;  nd = n; }
    else if (n < 1152) { src = wk + (n - 768) * 768;  th = 0.7f * sums[1] * (1.f / NK); dst = qw;  nd = n; }
    else if (n < 1536) { src = wv + (n - 1152) * 768; th = 0.7f * sums[2] * (1.f / NK); dst = qw;  nd = n; }
    else               { src = wo + (n - 1536) * 768; th = 0.7f * sums[3] * (1.f / NQ); dst = woq; nd = n - 1536; }
    const float4* sp = (const float4*)(src + k8 * 8);
    float4 v0 = sp[0], v1 = sp[1];
    float e[8] = {v0.x, v0.y, v0.z, v0.w, v1.x, v1.y, v1.z, v1.w};
    u16 o[8];
#pragma unroll
    for (int j = 0; j < 8; j++)
      o[j] = f2bf((fabsf(e[j]) >= th) ? ((e[j] > 0.f) ? 1.f : -1.f) : 0.f);
    __builtin_memcpy(dst + fidx(nd, k8 * 8), o, 16);
  } else if (i < 614400) {
    int j = i - 221184;
    int m = j / 96, k8 = j - m * 96;
    const float4* xp = (const float4*)(x + m * 768 + k8 * 8);
    float4 v0 = xp[0], v1 = xp[1];
    u16 o[8] = { f2bf(v0.x), f2bf(v0.y), f2bf(v0.z), f2bf(v0.w),
                 f2bf(v1.x), f2bf(v1.y), f2bf(v1.z), f2bf(v1.w) };
    __builtin_memcpy(xb + fidx(m, k8 * 8), o, 16);
  } else {
    int j = i - 614400;                         // [0, 65536)
    int s = j >> 5, c = j & 31;
    float f = exp2f((float)c * -0.41524101186092029f);   // 10000^(-c/32)
    float sn, cs; sincosf((float)s * f, &sn, &cs);
    rt[j] = make_float2(cs, sn);
  }
}

// ---------- 3) fused QKV GEMM: m97 single-buffer 2-barrier, 64m x 128n tile + RoPE ----------
// 1-D grid 768 (XCD-swizzled: tm contiguous per XCD -> A panel + B panel fit the 4 MB L2).
// 4 waves: wm = w&1 (32-row half), wn = w>>1 (64-col half = head). Per K-step (BK=64):
// 24 KB slab staged once (6 x 1 KB gload_lds16 per wave), 2 barriers, single buffer --
// at 3 blocks/CU the implicit wave overlap covers the stage stall, and the 768-block grid
// has perfect CU balance. (R8-measured)
__global__ __launch_bounds__(256, 3) void gemm_qkv_kernel(const u16* __restrict__ xb, const u16* __restrict__ qw,
                                                          const float* __restrict__ sums,
                                                          const float2* __restrict__ rt,
                                                          u16* __restrict__ qb, u16* __restrict__ kb,
                                                          u16* __restrict__ vT) {
  __shared__ u16 sm[24 * 512];   // chunks 0-7 = A (2 grp x 4 kc), 8-23 = B (4 grp x 4 kc)
  int v = xcd_swz768(blockIdx.x);
  int tm = v / 12, tn = v - tm * 12;
  int t = threadIdx.x, lane = t & 63, w = t >> 6, c = lane & 31, g2 = lane >> 5;
  int wm = w & 1, wn = w >> 1;
  int wn8 = wn * 8;

  f32x16 acc[2]; acc[0] = (f32x16)0.f; acc[1] = (f32x16)0.f;

  for (int s = 0; s < 12; ++s) {
#pragma unroll
    for (int i = 0; i < 6; i++) {
      int ch = w * 6 + i;
      const u16* src = (ch < 8)
        ? xb + (tm * 2 + (ch >> 2)) * 24576 + (s * 4 + (ch & 3)) * 512 + lane * 8
        : qw + (tn * 4 + (ch >> 2) - 2) * 24576 + (s * 4 + (ch & 3)) * 512 + lane * 8;
      gload_lds16(src, sm + ch * 512);
    }
    __syncthreads();                  // vmcnt(0) drained -> slab s visible
#pragma unroll
    for (int kc = 0; kc < 4; kc++) {
      bf16x8 a  = ldfrag(sm + (wm * 4 + kc) * 512 + lane * 8);
      bf16x8 b0 = ldfrag(sm + (8 + wn8 + kc) * 512 + lane * 8);
      bf16x8 b1 = ldfrag(sm + (12 + wn8 + kc) * 512 + lane * 8);
      acc[0] = mfma32_(a, b0, acc[0]);
      acc[1] = mfma32_(a, b1, acc[1]);
    }
    __syncthreads();                  // readers done before next stage overwrites
  }

  float sq = sums[0] * (1.f / NQ) * 0.180336880111120f;  // * 0.125 * log2(e)
  float sk = sums[1] * (1.f / NK);
  float sv = sums[2] * (1.f / NK);
  int mb = tm * 64 + wm * 32 + 4 * g2;
  if (tn < 9) {
    float sc = (tn < 6) ? sq : sk;
    int head = (tn < 6) ? (tn * 2 + wn) : ((tn - 6) * 2 + wn);
    const float2* rp = rt + c;                   // rt[s*32 + c], coalesced over lanes
#pragma unroll
    for (int r = 0; r < 16; r++) {
      int m = mb + (r & 3) + 8 * (r >> 2);
      int bb = m >> 11, s = m & 2047;
      float2 cs2 = rp[s << 5];
      float x1 = acc[0][r] * sc, x2 = acc[1][r] * sc;
      u16 y1 = f2bf(x1 * cs2.x - x2 * cs2.y);    // dim d = c
      u16 y2 = f2bf(x2 * cs2.x + x1 * cs2.y);    // dim d = c + 32
      if (tn < 6) {
        qb[qidx(bb, s, head, c)]      = y1;
        qb[qidx(bb, s, head, c + 32)] = y2;
      } else {
        kb[kidx(bb * 6 + head, s, c)]      = y1;
        kb[kidx(bb * 6 + head, s, c + 32)] = y2;
      }
    }
  } else {
    int kvh = (tn - 9) * 2 + wn;
#pragma unroll
    for (int nb = 0; nb < 2; nb++)
#pragma unroll
      for (int r = 0; r < 16; r++) {
        int m = mb + (r & 3) + 8 * (r >> 2);
        int bb = m >> 11, s = m & 2047;
        int sp = (s & ~12) | ((s & 4) << 1) | ((s & 8) >> 1);   // sigma: swap bits 2,3
        vT[vidx(bb * 6 + kvh, nb * 32 + c, sp)] = f2bf(acc[nb][r] * sv);
      }
  }
}

// ---------- 4) attention: barrier-free loop, 4-way key split, 2 q-tiles per wave ----------
// R8 structure with one ILP change: per key-group the pair of q-tile chains is explicitly
// interleaved -- QK0 -> sm0 -> [PV0 || QK1] -> sm1 -> PV1 -- so the 4 serially-dependent
// QK1 MFMAs issue under PV0's independent chains instead of after them. Per-accumulator
// op order is unchanged (bit-identical output); register envelope unchanged (S0 is packed
// into PA before S1 allocates, keeping peak live ~same as R8's sequential version).
__device__ __forceinline__ void attn_step_pair(const bf16x8 (&kf)[4], const bf16x8 (&vf)[2][2],
                                               const bf16x8 (&qf0)[4], const bf16x8 (&qf1)[4],
                                               f32x16 (&O0)[2], f32x16 (&O1)[2],
                                               float& lsum0, float& lsum1) {
  f32x16 S = (f32x16)0.f;
  __builtin_amdgcn_s_setprio(1);
#pragma unroll
  for (int ks = 0; ks < 4; ks++) S = mfma32_(kf[ks], qf0[ks], S);
  __builtin_amdgcn_s_setprio(0);
#pragma unroll
  for (int r = 0; r < 16; r++) S[r] = fexp2(S[r]);
  {
    f32x2 a0 = {S[0], S[1]},  a1 = {S[2], S[3]},  a2 = {S[4], S[5]},  a3 = {S[6], S[7]};
    f32x2 a4 = {S[8], S[9]},  a5 = {S[10], S[11]}, a6 = {S[12], S[13]}, a7 = {S[14], S[15]};
    f32x2 b0 = a0 + a1, b1 = a2 + a3, b2 = a4 + a5, b3 = a6 + a7;
    f32x2 c0 = b0 + b1, c1 = b2 + b3;
    f32x2 d = c0 + c1;
    lsum0 += d.x + d.y;
  }
  u32 P[8];
#pragma unroll
  for (int j = 0; j < 8; j++) P[j] = packbf(S[2 * j], S[2 * j + 1]);
  bf16x8 PA0, PA1;
  __builtin_memcpy(&PA0, &P[0], 16);
  __builtin_memcpy(&PA1, &P[4], 16);
  // PV0 interleaved with QK1: 3 independent MFMA chains in one priority window.
  f32x16 S1 = (f32x16)0.f;
  __builtin_amdgcn_s_setprio(1);
  O0[0] = mfma32_(PA0, vf[0][0], O0[0]);
  S1 = mfma32_(kf[0], qf1[0], S1);
  O0[1] = mfma32_(PA0, vf[1][0], O0[1]);
  S1 = mfma32_(kf[1], qf1[1], S1);
  O0[0] = mfma32_(PA1, vf[0][1], O0[0]);
  S1 = mfma32_(kf[2], qf1[2], S1);
  O0[1] = mfma32_(PA1, vf[1][1], O0[1]);
  S1 = mfma32_(kf[3], qf1[3], S1);
  __builtin_amdgcn_s_setprio(0);
#pragma unroll
  for (int r = 0; r < 16; r++) S1[r] = fexp2(S1[r]);
  {
    f32x2 a0 = {S1[0], S1[1]},  a1 = {S1[2], S1[3]},  a2 = {S1[4], S1[5]},  a3 = {S1[6], S1[7]};
    f32x2 a4 = {S1[8], S1[9]},  a5 = {S1[10], S1[11]}, a6 = {S1[12], S1[13]}, a7 = {S1[14], S1[15]};
    f32x2 b0 = a0 + a1, b1 = a2 + a3, b2 = a4 + a5, b3 = a6 + a7;
    f32x2 c0 = b0 + b1, c1 = b2 + b3;
    f32x2 d = c0 + c1;
    lsum1 += d.x + d.y;
  }
#pragma unroll
  for (int j = 0; j < 8; j++) P[j] = packbf(S1[2 * j], S1[2 * j + 1]);
  bf16x8 PB0, PB1;
  __builtin_memcpy(&PB0, &P[0], 16);
  __builtin_memcpy(&PB1, &P[4], 16);
  __builtin_amdgcn_s_setprio(1);
  O1[0] = mfma32_(PB0, vf[0][0], O1[0]);
  O1[1] = mfma32_(PB0, vf[1][0], O1[1]);
  O1[0] = mfma32_(PB1, vf[0][1], O1[0]);
  O1[1] = mfma32_(PB1, vf[1][1], O1[1]);
  __builtin_amdgcn_s_setprio(0);
}

__global__ __launch_bounds__(256, 3) void attn_kernel(const u16* __restrict__ qb, const u16* __restrict__ kb,
                                                      const u16* __restrict__ vT, u16* __restrict__ ab) {
  __shared__ float Obuf[4][32][66];
  __shared__ float Lbuf[4][32];
  int v = xcd_swz768(blockIdx.x);
  int bk = v >> 6, y = v & 63;
  int b = bk / 6, kvh = bk % 6;
  int qp = y & 31, h2 = y >> 5;
  int h = kvh * 2 + h2;
  int t = threadIdx.x, lane = t & 63, w = t >> 6, c = lane & 31, g2 = lane >> 5;

  const u16* q0 = qb + ((b * 64 + qp * 2) * 12 + h) * 2048 + lane * 8;
  const u16* q1 = q0 + 12 * 2048;
  bf16x8 qf0[4], qf1[4];
#pragma unroll
  for (int ks = 0; ks < 4; ks++) { qf0[ks] = ldfrag(q0 + ks * 512); qf1[ks] = ldfrag(q1 + ks * 512); }

  f32x16 fz = (f32x16)0.f;
  f32x16 O0[2] = {fz, fz}, O1[2] = {fz, fz};
  float lsum0 = 0.f, lsum1 = 0.f;

  const u16* Kb = kb + bk * 131072;
  const u16* Vb = vT + bk * 131072;

  for (int it = 0; it < 16; ++it) {
    int g = w * 16 + it;                        // this wave's key group (32 keys)
    const u16* kt = Kb + g * 2048 + lane * 8;
    const u16* vt = Vb + (g >> 1) * 4096 + (g & 1) * 1024 + lane * 8;
    bf16x8 kf[4], vf[2][2];
#pragma unroll
    for (int ks = 0; ks < 4; ks++) kf[ks] = ldfrag(kt + ks * 512);
#pragma unroll
    for (int dn = 0; dn < 2; dn++)
#pragma unroll
      for (int ksv = 0; ksv < 2; ksv++)
        vf[dn][ksv] = ldfrag(vt + dn * 2048 + ksv * 512);
    attn_step_pair(kf, vf, qf0, qf1, O0, O1, lsum0, lsum1);
  }

  float lt0 = lsum0 + __shfl_xor(lsum0, 32);    // combine g2 key-row halves per query col
  float lt1 = lsum1 + __shfl_xor(lsum1, 32);

  // two reduce passes (qi = 0, 1): 4 wave-partials -> one q-tile of output each
#pragma unroll
  for (int qi = 0; qi < 2; qi++) {
    if (qi) __syncthreads();                    // pass-0 reads done before overwrite
    if (g2 == 0) Lbuf[w][c] = qi ? lt1 : lt0;
    const f32x16* Ow = qi ? O1 : O0;
#pragma unroll
    for (int dn = 0; dn < 2; dn++)
#pragma unroll
      for (int r = 0; r < 16; r++)
        Obuf[w][(r & 3) + 8 * (r >> 2) + 4 * g2][dn * 32 + c] = Ow[dn][r];
    __syncthreads();
    int qq = t >> 3, col8 = (t & 7) * 8;
    float l = Lbuf[0][qq] + Lbuf[1][qq] + Lbuf[2][qq] + Lbuf[3][qq];
    float inv = 1.f / l;
    u16 o[8];
#pragma unroll
    for (int j = 0; j < 8; j++)
      o[j] = f2bf((Obuf[0][qq][col8 + j] + Obuf[1][qq][col8 + j] +
                   Obuf[2][qq][col8 + j] + Obuf[3][qq][col8 + j]) * inv);
    int mg = b * 64 + qp * 2 + qi;
    u16* dst = ab + mg * 24576 + ((h * 64 + col8) >> 4) * 512 + ((col8 >> 3) & 1) * 256 + qq * 8;
    __builtin_memcpy(dst, o, 16);
  }
}

// ---------- 5) output projection GEMM (direct, barrier-free, SW-pipelined, 64m x 64n) -> fp32 ----------
// R8-measured version. 1-D grid 768, XCD-swizzled (tm contiguous per XCD).
__global__ __launch_bounds__(256, 3) void gemm_out_kernel(const u16* __restrict__ ab, const u16* __restrict__ woq,
                                                          const float* __restrict__ sums, float* __restrict__ out) {
  int v = xcd_swz768(blockIdx.x);
  int tm = v / 12, tn = v - tm * 12;
  int t = threadIdx.x, lane = t & 63, w = t >> 6, c = lane & 31, g2 = lane >> 5;
  int wm = w & 1, wn = w >> 1;
  const u16* abase = ab + (tm * 2 + wm) * 24576 + lane * 8;
  const u16* bbase = woq + (tn * 2 + wn) * 24576 + lane * 8;
  f32x16 acc = (f32x16)0.f;
  bf16x8 aA[4], bA[4], aB[4], bB[4];
#pragma unroll
  for (int ks = 0; ks < 4; ks++) {
    aA[ks] = ldfrag(abase + ks * 512);
    bA[ks] = ldfrag(bbase + ks * 512);
  }
#pragma unroll
  for (int kk = 0; kk < 48; kk += 8) {
#pragma unroll
    for (int ks = 0; ks < 4; ks++) {
      aB[ks] = ldfrag(abase + (kk + 4 + ks) * 512);
      bB[ks] = ldfrag(bbase + (kk + 4 + ks) * 512);
    }
#pragma unroll
    for (int ks = 0; ks < 4; ks++) acc = mfma32_(aA[ks], bA[ks], acc);
    if (kk + 8 < 48) {
#pragma unroll
      for (int ks = 0; ks < 4; ks++) {
        aA[ks] = ldfrag(abase + (kk + 8 + ks) * 512);
        bA[ks] = ldfrag(bbase + (kk + 8 + ks) * 512);
      }
    }
#pragma unroll
    for (int ks = 0; ks < 4; ks++) acc = mfma32_(aB[ks], bB[ks], acc);
  }
  float so = sums[3] * (1.f / NQ);
  int mb = tm * 64 + wm * 32 + 4 * g2;
#pragma unroll
  for (int r = 0; r < 16; r++) {
    int m = mb + (r & 3) + 8 * (r >> 2);
    out[m * 768 + tn * 64 + wn * 32 + c] = acc[r] * so;
  }
}

// ---------- launch ----------
extern "C" void kernel_launch(void* const* d_in, const int* in_sizes, int n_in,
                              void* d_out, int out_size, void* d_ws, size_t ws_size,
                              hipStream_t stream) {
  const float* x  = (const float*)d_in[0];
  const float* wq = (const float*)d_in[1];
  const float* wk = (const float*)d_in[2];
  const float* wv = (const float*)d_in[3];
  const float* wo = (const float*)d_in[4];
  float* out = (float*)d_out;
  char* ws = (char*)d_ws;

  float* sums = (float*)ws;                    // 16 B
  u16* qw  = (u16*)(ws + 256);                 // ternary QKV weights, fragment-tiled (1536 rows)
  u16* woq = (u16*)(ws + 2359552);             // ternary O weights, fragment-tiled (768 rows)
  u16* xb  = (u16*)(ws + 3539200);             // x fragment-tiled
  u16* qb  = (u16*)(ws + 9830656);             // Q' fragment-tiled
  u16* kb  = (u16*)(ws + 16122112);            // K' fragment-tiled
  u16* vT  = (u16*)(ws + 19267840);            // V' fragment-tiled, key-permuted
  u16* ab  = (u16*)(ws + 22413568);            // attn out fragment-tiled (ends at 28705024)
  float2* rt = (float2*)(ws + 28705024);       // RoPE table [2048][32] (cos, sin) = 512 KB

  hipMemsetAsync(sums, 0, 16, stream);
  dim3 blk(256);
  abssum_kernel<<<dim3(64, 4), blk, 0, stream>>>(wq, wk, wv, wo, sums);
  prep_kernel<<<dim3(2656), blk, 0, stream>>>(wq, wk, wv, wo, sums, x, qw, woq, xb, rt);
  gemm_qkv_kernel<<<dim3(768), blk, 0, stream>>>(xb, qw, sums, rt, qb, kb, vT);
  attn_kernel<<<dim3(768), blk, 0, stream>>>(qb, kb, vT, ab);
  gemm_out_kernel<<<dim3(768), blk, 0, stream>>>(ab, woq, sums, out);
}